// Round 22
// baseline (1697.817 us; speedup 1.0000x reference)
//
#include <hip/hip_runtime.h>

// ---------------------------------------------------------------------------
// NER CRF LSTM on MI355X. Round 21: R14 + lgkm-only barriers + background
// x L2-warming.
// R20 post-mortem: smaller fan-in regressed (8-wave barriers, halved issue
// concurrency). R14 stays. This round removes the hidden vmcnt(0) drain that
// __syncthreads imposes per barrier (which serialized the previous publish
// store's ack and foregrounded any background traffic):
//  1. step barriers = "s_waitcnt lgkmcnt(0); s_barrier" (memory-clobber asm).
//     LDS visibility only needs lgkm; publish stores drain in background.
//     h_tile double-buffered to close the one cross-step LDS reuse hazard.
//  2. x L2-warming via cached global_load_lds into a never-read dummy sink
//     (R16-proven correctness-neutral) — now genuinely background, turning
//     next step's x first-touch into an L2 hit.
// Sentinel data-as-flag protocol unchanged (R9-R14).
// ws layout: xfrag 32MB | h_hist 64MB | feats 1.5MB | bar 4KB (start ctr).
// ---------------------------------------------------------------------------

#define B_ 64
#define T_ 512
#define E_ 512
#define H_ 512
#define NTAGS 12
#define START_ID_ 10
#define STOP_ID_ 11
#define TILE_ 8192            // xfrag tile elems: 64 chunks * 16 rows * 8
#define SENT_ 0x7FC17FC1u     // dword of two bf16 NaNs: never real h data

typedef __attribute__((ext_vector_type(8))) short s8v;     // 8 x bf16 bits
typedef __attribute__((ext_vector_type(4))) float f32x4;   // MFMA acc
typedef __attribute__((ext_vector_type(4))) unsigned u4v;  // dword view

// lgkm-only block barrier: orders LDS ops, does NOT drain vmcnt.
#define BAR_LGKM() asm volatile("s_waitcnt lgkmcnt(0)\n\ts_barrier" ::: "memory")

__device__ __forceinline__ unsigned short f2bf(float f) {
    unsigned u = __float_as_uint(f);
    u += 0x7fffu + ((u >> 16) & 1u);           // RNE
    return (unsigned short)(u >> 16);
}
__device__ __forceinline__ float bf2f(unsigned short h) {
    return __uint_as_float(((unsigned)h) << 16);
}
__device__ __forceinline__ float sigm(float x) { return 1.f / (1.f + __expf(-x)); }
__device__ __forceinline__ float tanh_f(float x) { return 1.f - 2.f / (__expf(2.f * x) + 1.f); }

__device__ __forceinline__ void mfma_bf16(f32x4& c, s8v a, s8v b) {
    asm("v_mfma_f32_16x16x32_bf16 %0, %1, %2, %0" : "+v"(c) : "v"(a), "v"(b));
}

// Device-coherent (bypass L1/L2, LLC) ops; waitcnt inside the asm block
// (spill-safe by construction — R15/R16 lesson).
__device__ __forceinline__ unsigned load_flag(const unsigned* p) {
    unsigned r;
    asm volatile("global_load_dword %0, %1, off sc0 sc1\n\ts_waitcnt vmcnt(0)"
                 : "=v"(r) : "v"(p) : "memory");
    return r;
}
__device__ __forceinline__ void store_llc_b128(unsigned short* p, s8v v) {
    asm volatile("global_store_dwordx4 %0, %1, off sc0 sc1" :: "v"(p), "v"(v) : "memory");
}
// 4 bypass loads + drain in ONE asm block; outputs complete before asm ends.
__device__ __forceinline__ void reload4_llc(s8v& a0, s8v& a1, s8v& a2, s8v& a3,
    const unsigned short* p0, const unsigned short* p1,
    const unsigned short* p2, const unsigned short* p3)
{
    asm volatile(
        "global_load_dwordx4 %0, %4, off sc0 sc1\n\t"
        "global_load_dwordx4 %1, %5, off sc0 sc1\n\t"
        "global_load_dwordx4 %2, %6, off sc0 sc1\n\t"
        "global_load_dwordx4 %3, %7, off sc0 sc1\n\t"
        "s_waitcnt vmcnt(0)"
        : "=&v"(a0), "=&v"(a1), "=&v"(a2), "=&v"(a3)
        : "v"(p0), "v"(p1), "v"(p2), "v"(p3)
        : "memory");
}

// ---------------------------------------------------------------------------
// Kernel 1: embedding gather + fp32->bf16 into fragment-linear tiles.
// ---------------------------------------------------------------------------
__global__ __launch_bounds__(256) void embed_gather(
    const int* __restrict__ x, const float* __restrict__ embed,
    unsigned short* __restrict__ xfrag)
{
    const int q = blockIdx.x >> 9;          // batch group 0..3
    const int t = blockIdx.x & 511;
    const int fr = threadIdx.x & 15;
    const int c  = threadIdx.x >> 4;        // 0..15, owns dims c*32..c*32+31
    const int tok = x[(size_t)(q * 16 + fr) * T_ + t];
    const float* src = embed + (size_t)tok * E_ + c * 32;
    unsigned short* dst = xfrag + (size_t)(q * T_ + t) * TILE_;
#pragma unroll
    for (int g = 0; g < 4; g++) {
        float4 a = *(const float4*)(src + g * 8);
        float4 b = *(const float4*)(src + g * 8 + 4);
        s8v o;
        o[0] = (short)f2bf(a.x); o[1] = (short)f2bf(a.y);
        o[2] = (short)f2bf(a.z); o[3] = (short)f2bf(a.w);
        o[4] = (short)f2bf(b.x); o[5] = (short)f2bf(b.y);
        o[6] = (short)f2bf(b.z); o[7] = (short)f2bf(b.w);
        *(s8v*)(dst + (c * 4 + g) * 128 + fr * 8) = o;
    }
}

// ---------------------------------------------------------------------------
// Kernel 2: persistent BiLSTM. 256 blocks x 256 threads, 1 block/CU.
// ---------------------------------------------------------------------------
__global__ __launch_bounds__(256, 1) void lstm_persistent(
    const unsigned short* __restrict__ xfrag,
    const float* __restrict__ Wih_f, const float* __restrict__ Whh_f,
    const float* __restrict__ bih_f, const float* __restrict__ bhh_f,
    const float* __restrict__ Wih_b, const float* __restrict__ Whh_b,
    const float* __restrict__ bih_b, const float* __restrict__ bhh_b,
    unsigned short* __restrict__ h_hist, unsigned* __restrict__ bar)
{
    const int team = blockIdx.x & 7;
    const int dir = team & 1;
    const int q   = team >> 1;               // batch quarter
    const int b0  = q * 16;
    const int j0  = (blockIdx.x >> 3) * 16;  // h-dim base
    const int tid  = threadIdx.x;
    const int wave = tid >> 6;
    const int lane = tid & 63;

    const int fr = lane & 15;
    const int fk = (lane >> 4) * 8;
    const int arow = lane & 15;
    const int kgrp = lane >> 4;
    const int g_own = (lane >> 2) & 3;
    const int jloc  = lane & 3;
    const int j_own = j0 + wave * 4 + jloc;

    const float* Wih = dir ? Wih_b : Wih_f;
    const float* Whh = dir ? Whh_b : Whh_f;
    const float* bih = dir ? bih_b : bih_f;
    const float* bhh = dir ? bhh_b : bhh_f;

    __shared__ __align__(16) unsigned short Abuf[2][16 * 512];  // h dbuf, swizzled
    __shared__ __align__(16) unsigned short h_tile[2][16][16];  // 1KB dbuf repack
    __shared__ __align__(16) unsigned short warm_dummy[512];    // 1KB sink, never read

    // ---- sentinel-prefill this block's OWN h slice (all t), write-through ----
    {
        const int row = lane >> 2;
        const int seg = lane & 3;
        s8v sv;
#pragma unroll
        for (int e = 0; e < 8; e++) sv[e] = (short)0x7FC1;
        if (seg < 2) {
            for (int tt = wave * 2 + seg; tt < T_; tt += 8) {
                unsigned short* p = h_hist +
                    (((size_t)dir * T_ + tt) * B_ + (b0 + row)) * H_ + j0 + 0;
                store_llc_b128(p, sv);
                store_llc_b128(p + 8, sv);
            }
        }
    }

    // ---- weight B-fragments (wave-column layout). ----
    const int wrow = (fr >> 2) * 512 + j0 + wave * 4 + (fr & 3);
    const float* whr = Whh + (size_t)wrow * 512;
    const float* wxr = Wih + (size_t)wrow * 512;
    s8v bh[16], bx[16];
#pragma unroll
    for (int kk = 0; kk < 16; kk++) {
        s8v v, w;
#pragma unroll
        for (int j = 0; j < 8; j++) {
            v[j] = (short)f2bf(whr[kk * 32 + fk + j]);
            w[j] = (short)f2bf(wxr[kk * 32 + fk + j]);
        }
        bh[kk] = v; bx[kk] = w;
    }

    float bias_[4];
#pragma unroll
    for (int r = 0; r < 4; r++) bias_[r] = bih[r * 512 + j_own] + bhh[r * 512 + j_own];

    // ---- one-time grid start barrier: all prefills visible before any write --
    {
        asm volatile("s_waitcnt vmcnt(0)" ::: "memory");
        __syncthreads();
        if (tid == 0) {
            __hip_atomic_fetch_add(bar + 1023, 1u, __ATOMIC_RELAXED,
                                   __HIP_MEMORY_SCOPE_AGENT);
            for (;;) {
                unsigned v = load_flag(bar + 1023);
                if (v >= 256u) break;
                __builtin_amdgcn_s_sleep(8);
            }
        }
        __syncthreads();
    }

    float c_state = 0.f;
    const unsigned short* xteam = xfrag + (size_t)q * T_ * TILE_;

    for (int s = 0; s < T_; s++) {
        const int t = dir ? (T_ - 1 - s) : s;
        const int tprev = dir ? (t + 1) : (t - 1);
        f32x4 ac0 = {0.f,0.f,0.f,0.f}, ac1 = {0.f,0.f,0.f,0.f};
        f32x4 ac2 = {0.f,0.f,0.f,0.f}, ac3 = {0.f,0.f,0.f,0.f};

        // ---- x phase: cached fragment loads + 4-chain MFMAs ----
        {
            const unsigned short* xp = xteam + (size_t)t * TILE_ + lane * 8;
            s8v xa[16];
#pragma unroll
            for (int kk = 0; kk < 16; kk++) xa[kk] = *(const s8v*)(xp + kk * 512);
#pragma unroll
            for (int m = 0; m < 4; m++) {
                mfma_bf16(ac0, xa[4 * m],     bx[4 * m]);
                mfma_bf16(ac1, xa[4 * m + 1], bx[4 * m + 1]);
                mfma_bf16(ac2, xa[4 * m + 2], bx[4 * m + 2]);
                mfma_bf16(ac3, xa[4 * m + 3], bx[4 * m + 3]);
            }
        }

        s8v hv4[4];
        if (s > 0) {
            // ---- h tile, first attempt = plain cached (L2-shared). Fence
            //      pins issue after the x phase (R13 lesson). ----
            asm volatile("" ::: "memory");
#pragma unroll
            for (int u = 0; u < 4; u++) {
                int ch = tid + u * 256;
                int r = ch >> 6, c = ch & 63;
                hv4[u] = *(const s8v*)(h_hist +
                        (((size_t)dir * T_ + tprev) * B_ + (b0 + r)) * H_ + c * 8);
            }
        }

        // ---- background x warming for step s+1 (cached, dummy LDS sink,
        //      never drained by the lgkm-only barriers below). ----
        if (s < T_ - 1) {
            const int tn = dir ? (t - 1) : (t + 1);
            const unsigned short* wbase = xteam + (size_t)tn * TILE_;
#pragma unroll
            for (int u = 0; u < 4; u++) {
                const unsigned short* gsrc = wbase + (wave * 4 + u) * 512 + lane * 8;
                __builtin_amdgcn_global_load_lds(
                    (const __attribute__((address_space(1))) void*)gsrc,
                    (__attribute__((address_space(3))) void*)warm_dummy,
                    16, 0, 0 /* cached */);
            }
        }

        if (s > 0) {
            // ---- sentinel verify; dirty -> spill-safe one-block retry ----
            const unsigned short* hrow = h_hist +
                (((size_t)dir * T_ + tprev) * B_) * H_;
            for (;;) {
                bool dirty = false;
#pragma unroll
                for (int u = 0; u < 4; u++) {
                    u4v w = *(u4v*)&hv4[u];
#pragma unroll
                    for (int e = 0; e < 4; e++) dirty |= (w[e] == SENT_);
                }
                if (__ballot(dirty) == 0ull) break;
                __builtin_amdgcn_s_sleep(1);
                const unsigned short* p0 = hrow + (size_t)(b0 + ((tid + 0)   >> 6)) * H_ + ((tid + 0)   & 63) * 8;
                const unsigned short* p1 = hrow + (size_t)(b0 + ((tid + 256) >> 6)) * H_ + ((tid + 256) & 63) * 8;
                const unsigned short* p2 = hrow + (size_t)(b0 + ((tid + 512) >> 6)) * H_ + ((tid + 512) & 63) * 8;
                const unsigned short* p3 = hrow + (size_t)(b0 + ((tid + 768) >> 6)) * H_ + ((tid + 768) & 63) * 8;
                reload4_llc(hv4[0], hv4[1], hv4[2], hv4[3], p0, p1, p2, p3);
            }
            // ---- LDS stage + h-MFMAs ----
            unsigned short* buf = Abuf[s & 1];
#pragma unroll
            for (int u = 0; u < 4; u++) {
                int ch = tid + u * 256;
                int r = ch >> 6, c = ch & 63;
                *(s8v*)(buf + r * 512 + ((c ^ (r & 7)) << 3)) = hv4[u];
            }
            BAR_LGKM();                            // barrier 1: stage-ready
#pragma unroll
            for (int kk = 0; kk < 16; kk++) {
                int slot = (kk * 4 + kgrp) ^ (arow & 7);
                s8v a = *(const s8v*)(buf + arow * 512 + slot * 8);
                if      ((kk & 3) == 0) mfma_bf16(ac0, a, bh[kk]);
                else if ((kk & 3) == 1) mfma_bf16(ac1, a, bh[kk]);
                else if ((kk & 3) == 2) mfma_bf16(ac2, a, bh[kk]);
                else                    mfma_bf16(ac3, a, bh[kk]);
            }
        }

        float acc[4];
#pragma unroll
        for (int r = 0; r < 4; r++) acc[r] = (ac0[r] + ac1[r]) + (ac2[r] + ac3[r]);

        // ---- Eklundh 4x4 transpose across g (lane masks 4, 8) ----
        float p0 = __shfl_xor(acc[0], 4, 64);
        float p1 = __shfl_xor(acc[1], 4, 64);
        float p2 = __shfl_xor(acc[2], 4, 64);
        float p3 = __shfl_xor(acc[3], 4, 64);
        const bool glo = (g_own & 1);
        float m1_0 = glo ? p1 : acc[0];
        float m1_1 = glo ? acc[1] : p0;
        float m1_2 = glo ? p3 : acc[2];
        float m1_3 = glo ? acc[3] : p2;
        float q0 = __shfl_xor(m1_0, 8, 64);
        float q1 = __shfl_xor(m1_1, 8, 64);
        float q2 = __shfl_xor(m1_2, 8, 64);
        float q3 = __shfl_xor(m1_3, 8, 64);
        const bool ghi = (g_own >> 1) & 1;
        float gi = (ghi ? q2   : m1_0) + bias_[0];
        float gf = (ghi ? q3   : m1_1) + bias_[1];
        float gg = (ghi ? m1_2 : q0)   + bias_[2];
        float go = (ghi ? m1_3 : q1)   + bias_[3];

        // ---- activations; thread owns (b0 + kgrp*4 + g_own, j_own) ----
        c_state = sigm(gf) * c_state + sigm(gi) * tanh_f(gg);
        float hv = sigm(go) * tanh_f(c_state);

        // ---- publish: dbuf LDS repack -> wave0 coalesced 16B bursts ----
        h_tile[s & 1][kgrp * 4 + g_own][wave * 4 + jloc] = f2bf(hv);
        BAR_LGKM();                                // barrier 2: h_tile-ready
        if (wave == 0 && lane < 32) {
            int row = lane >> 1, seg = lane & 1;
            s8v v = *(const s8v*)&h_tile[s & 1][row][seg * 8];
            store_llc_b128(h_hist +
                (((size_t)dir * T_ + t) * B_ + (b0 + row)) * H_ + j0 + seg * 8, v);
        }
        // no ack, no flag: consumers sentinel-verify
    }
}

// ---------------------------------------------------------------------------
// Kernel 3: feats[b,t,k] = [h_f|h_b] . W_out[k] + b_out[k].
// ---------------------------------------------------------------------------
__global__ __launch_bounds__(256) void feats_kernel(
    const unsigned short* __restrict__ h_hist,
    const float* __restrict__ W_out, const float* __restrict__ b_out,
    float* __restrict__ feats)
{
    __shared__ float wlds[NTAGS * 1024];
    __shared__ float blds[NTAGS];
    for (int i = threadIdx.x; i < NTAGS * 1024; i += 256) wlds[i] = W_out[i];
    if (threadIdx.x < NTAGS) blds[threadIdx.x] = b_out[threadIdx.x];
    __syncthreads();

    int lane = threadIdx.x & 63;
    int row0 = blockIdx.x * 32 + (threadIdx.x >> 6) * 8;
    for (int rr = 0; rr < 8; rr++) {
        int wid = row0 + rr;                 // row = b*T + t
        int b = wid >> 9, t = wid & 511;
        s8v vf = *(const s8v*)(h_hist + (((size_t)0 * T_ + t) * B_ + b) * H_ + lane * 8);
        s8v vb = *(const s8v*)(h_hist + (((size_t)1 * T_ + t) * B_ + b) * H_ + lane * 8);
        float xf[8], xb[8];
#pragma unroll
        for (int j = 0; j < 8; j++) {
            xf[j] = bf2f((unsigned short)vf[j]);
            xb[j] = bf2f((unsigned short)vb[j]);
        }
#pragma unroll
        for (int k = 0; k < NTAGS; k++) {
            float acc = 0.f;
#pragma unroll
            for (int j = 0; j < 8; j++) acc += xf[j] * wlds[k * 1024 + lane * 8 + j];
#pragma unroll
            for (int j = 0; j < 8; j++) acc += xb[j] * wlds[k * 1024 + 512 + lane * 8 + j];
#pragma unroll
            for (int off = 32; off > 0; off >>= 1) acc += __shfl_xor(acc, off, 64);
            if (lane == 0) feats[(size_t)wid * NTAGS + k] = acc + blds[k];
        }
    }
}

// ---------------------------------------------------------------------------
// Kernel 4: Viterbi. One wave per batch item; lane j<12 owns tag j.
// ---------------------------------------------------------------------------
__global__ __launch_bounds__(64) void viterbi_kernel(
    const float* __restrict__ feats, const float* __restrict__ trans,
    float* __restrict__ out)
{
    const int b = blockIdx.x;
    const int j = threadIdx.x;
    const int jj = (j < NTAGS) ? j : 0;    // safe index for inactive lanes
    __shared__ unsigned char bp[T_][NTAGS];
    __shared__ float flds[T_ * NTAGS];     // 24KB

    {
        const float4* src = (const float4*)(feats + (size_t)b * T_ * NTAGS);
        float4* dst = (float4*)flds;
        for (int i = j; i < T_ * NTAGS / 4; i += 64) dst[i] = src[i];
    }
    __syncthreads();

    float trow[NTAGS];
#pragma unroll
    for (int p = 0; p < NTAGS; p++) trow[p] = trans[jj * NTAGS + p];
    float fv = (j == START_ID_) ? 0.f : -10000.f;

    for (int t = 0; t < T_; t++) {
        float feat = flds[t * NTAGS + jj];
        float best = -3.4e38f; int bestp = 0;
#pragma unroll
        for (int p = 0; p < NTAGS; p++) {
            float sp = __shfl(fv, p, 64) + trow[p];    // all lanes participate
            if (sp > best) { best = sp; bestp = p; }   // strict > == argmax-first
        }
        fv = best + feat;
        if (j < NTAGS) bp[t][j] = (unsigned char)bestp;
    }

    float term = (j < NTAGS) ? (fv + trans[STOP_ID_ * NTAGS + jj]) : -3.4e38f;
    float best = -3.4e38f; int bt = 0;
#pragma unroll
    for (int p = 0; p < NTAGS; p++) {
        float v = __shfl(term, p, 64);
        if (v > best) { best = v; bt = p; }
    }
    __syncthreads();
    if (j == 0) {
        out[b] = best;
        int tag = bt;
        for (int t = T_ - 1; t >= 0; t--) {
            out[B_ + (size_t)b * T_ + t] = (float)tag;
            tag = bp[t][tag];
        }
    }
}

// ---------------------------------------------------------------------------
extern "C" void kernel_launch(void* const* d_in, const int* in_sizes, int n_in,
                              void* d_out, int out_size, void* d_ws, size_t ws_size,
                              hipStream_t stream)
{
    (void)in_sizes; (void)n_in; (void)out_size; (void)ws_size;
    const int*   x     = (const int*)  d_in[0];
    const float* embed = (const float*)d_in[1];
    const float* Wih_f = (const float*)d_in[2];
    const float* Whh_f = (const float*)d_in[3];
    const float* bih_f = (const float*)d_in[4];
    const float* bhh_f = (const float*)d_in[5];
    const float* Wih_b = (const float*)d_in[6];
    const float* Whh_b = (const float*)d_in[7];
    const float* bih_b = (const float*)d_in[8];
    const float* bhh_b = (const float*)d_in[9];
    const float* W_out = (const float*)d_in[10];
    const float* b_out = (const float*)d_in[11];
    const float* trans = (const float*)d_in[12];

    char* ws = (char*)d_ws;
    const size_t XF_BYTES   = (size_t)4 * T_ * TILE_ * 2;     // 32 MB
    const size_t HIST_BYTES = (size_t)2 * T_ * B_ * H_ * 2;   // 64 MB
    const size_t FEAT_BYTES = (size_t)B_ * T_ * NTAGS * 4;    // 1.5 MB
    unsigned short* xfrag  = (unsigned short*)(ws);
    unsigned short* h_hist = (unsigned short*)(ws + XF_BYTES);
    float*          feats  = (float*)(ws + XF_BYTES + HIST_BYTES);
    unsigned*       bar    = (unsigned*)(ws + XF_BYTES + HIST_BYTES + FEAT_BYTES);

    hipMemsetAsync(bar, 0, 4096, stream);
    embed_gather<<<dim3(2048), dim3(256), 0, stream>>>(x, embed, xfrag);
    lstm_persistent<<<dim3(256), dim3(256), 0, stream>>>(xfrag,
        Wih_f, Whh_f, bih_f, bhh_f, Wih_b, Whh_b, bih_b, bhh_b, h_hist, bar);
    feats_kernel<<<dim3(1024), dim3(256), 0, stream>>>(h_hist, W_out, b_out, feats);
    viterbi_kernel<<<dim3(B_), dim3(64), 0, stream>>>(feats, trans, (float*)d_out);
}

// Round 23
// 1401.713 us; speedup vs baseline: 1.2112x; 1.2112x over previous
//
#include <hip/hip_runtime.h>

// ---------------------------------------------------------------------------
// NER CRF LSTM on MI355X. Round 23: restore R14 (empirical best: 1178us lstm,
// 1403us total). Nine variants around this structure all regressed or failed:
//  - earlier/any speculation of h (R13/R15): sentinel storm or spill bug
//  - x warming (R16/R21): foregrounds traffic at vm-drains / breaks write-
//    combining (WRITE_SIZE +66MB in R21)
//  - lgkm-only barriers (R21): publish stream loses coalescing
//  - no-LDS fragment h (R18): 4x redundant LLC pulls
//  - 16-member teams (R20): pricier 8-wave barriers, less issue concurrency
// R14 = R10 structure + cached-first-attempt h read (L2 skew compression),
// sentinel data-as-flag protocol, zero flags/acks. This is the converged
// design: per-step cost ~= 2 LLC RTTs + ~2000cy serial compute (latency-
// bound; MfmaUtil/HBM% are not the binding constraints).
// ws layout: xfrag 32MB | h_hist 64MB | feats 1.5MB | bar 4KB (start ctr).
// ---------------------------------------------------------------------------

#define B_ 64
#define T_ 512
#define E_ 512
#define H_ 512
#define NTAGS 12
#define START_ID_ 10
#define STOP_ID_ 11
#define TILE_ 8192            // xfrag tile elems: 64 chunks * 16 rows * 8
#define SENT_ 0x7FC17FC1u     // dword of two bf16 NaNs: never real h data

typedef __attribute__((ext_vector_type(8))) short s8v;     // 8 x bf16 bits
typedef __attribute__((ext_vector_type(4))) float f32x4;   // MFMA acc
typedef __attribute__((ext_vector_type(4))) unsigned u4v;  // dword view
typedef __attribute__((ext_vector_type(2))) unsigned u2v;  // 8B store payload

__device__ __forceinline__ unsigned short f2bf(float f) {
    unsigned u = __float_as_uint(f);
    u += 0x7fffu + ((u >> 16) & 1u);           // RNE
    return (unsigned short)(u >> 16);
}
__device__ __forceinline__ float bf2f(unsigned short h) {
    return __uint_as_float(((unsigned)h) << 16);
}
__device__ __forceinline__ float sigm(float x) { return 1.f / (1.f + __expf(-x)); }
__device__ __forceinline__ float tanh_f(float x) { return 1.f - 2.f / (__expf(2.f * x) + 1.f); }

__device__ __forceinline__ void mfma_bf16(f32x4& c, s8v a, s8v b) {
    asm("v_mfma_f32_16x16x32_bf16 %0, %1, %2, %0" : "+v"(c) : "v"(a), "v"(b));
}

// Device-coherent (bypass L1/L2, LLC) ops.
__device__ __forceinline__ unsigned load_flag(const unsigned* p) {
    unsigned r;
    asm volatile("global_load_dword %0, %1, off sc0 sc1\n\ts_waitcnt vmcnt(0)"
                 : "=v"(r) : "v"(p) : "memory");
    return r;
}
__device__ __forceinline__ void store_llc_b64(unsigned short* p, u2v v) {
    asm volatile("global_store_dwordx2 %0, %1, off sc0 sc1" :: "v"(p), "v"(v) : "memory");
}
__device__ __forceinline__ void store_llc_b128(unsigned short* p, s8v v) {
    asm volatile("global_store_dwordx4 %0, %1, off sc0 sc1" :: "v"(p), "v"(v) : "memory");
}

// ---------------------------------------------------------------------------
// Kernel 1: embedding gather + fp32->bf16 into fragment-linear tiles.
// ---------------------------------------------------------------------------
__global__ __launch_bounds__(256) void embed_gather(
    const int* __restrict__ x, const float* __restrict__ embed,
    unsigned short* __restrict__ xfrag)
{
    const int q = blockIdx.x >> 9;          // batch group 0..3
    const int t = blockIdx.x & 511;
    const int fr = threadIdx.x & 15;
    const int c  = threadIdx.x >> 4;        // 0..15, owns dims c*32..c*32+31
    const int tok = x[(size_t)(q * 16 + fr) * T_ + t];
    const float* src = embed + (size_t)tok * E_ + c * 32;
    unsigned short* dst = xfrag + (size_t)(q * T_ + t) * TILE_;
#pragma unroll
    for (int g = 0; g < 4; g++) {
        float4 a = *(const float4*)(src + g * 8);
        float4 b = *(const float4*)(src + g * 8 + 4);
        s8v o;
        o[0] = (short)f2bf(a.x); o[1] = (short)f2bf(a.y);
        o[2] = (short)f2bf(a.z); o[3] = (short)f2bf(a.w);
        o[4] = (short)f2bf(b.x); o[5] = (short)f2bf(b.y);
        o[6] = (short)f2bf(b.z); o[7] = (short)f2bf(b.w);
        *(s8v*)(dst + (c * 4 + g) * 128 + fr * 8) = o;
    }
}

// ---------------------------------------------------------------------------
// Kernel 2: persistent BiLSTM. 256 blocks x 256 threads, 1 block/CU.
// ---------------------------------------------------------------------------
__global__ __launch_bounds__(256, 1) void lstm_persistent(
    const unsigned short* __restrict__ xfrag,
    const float* __restrict__ Wih_f, const float* __restrict__ Whh_f,
    const float* __restrict__ bih_f, const float* __restrict__ bhh_f,
    const float* __restrict__ Wih_b, const float* __restrict__ Whh_b,
    const float* __restrict__ bih_b, const float* __restrict__ bhh_b,
    unsigned short* __restrict__ h_hist, unsigned* __restrict__ bar)
{
    const int team = blockIdx.x & 7;
    const int dir = team & 1;
    const int q   = team >> 1;               // batch quarter
    const int b0  = q * 16;
    const int j0  = (blockIdx.x >> 3) * 16;  // h-dim base
    const int tid  = threadIdx.x;
    const int wave = tid >> 6;
    const int lane = tid & 63;

    const int fr = lane & 15;
    const int fk = (lane >> 4) * 8;
    const int arow = lane & 15;
    const int kgrp = lane >> 4;
    const int g_own = (lane >> 2) & 3;
    const int jloc  = lane & 3;
    const int j_own = j0 + wave * 4 + jloc;

    const float* Wih = dir ? Wih_b : Wih_f;
    const float* Whh = dir ? Whh_b : Whh_f;
    const float* bih = dir ? bih_b : bih_f;
    const float* bhh = dir ? bhh_b : bhh_f;

    __shared__ __align__(16) unsigned short Abuf[2][16 * 512]; // h double-buffer, swizzled
    __shared__ __align__(16) unsigned short h_tile[16][16];    // 512B repack tile

    // ---- sentinel-prefill this block's OWN h slice (all t), write-through ----
    {
        const int row = lane >> 2;
        const int dwp = lane & 3;
        u2v sv; sv[0] = SENT_; sv[1] = SENT_;
        for (int tt = wave; tt < T_; tt += 4) {
            unsigned short* p = h_hist +
                (((size_t)dir * T_ + tt) * B_ + (b0 + row)) * H_ + j0 + dwp * 4;
            store_llc_b64(p, sv);
        }
    }

    // ---- weight B-fragments (wave-column layout). ----
    const int wrow = (fr >> 2) * 512 + j0 + wave * 4 + (fr & 3);
    const float* whr = Whh + (size_t)wrow * 512;
    const float* wxr = Wih + (size_t)wrow * 512;
    s8v bh[16], bx[16];
#pragma unroll
    for (int kk = 0; kk < 16; kk++) {
        s8v v, w;
#pragma unroll
        for (int j = 0; j < 8; j++) {
            v[j] = (short)f2bf(whr[kk * 32 + fk + j]);
            w[j] = (short)f2bf(wxr[kk * 32 + fk + j]);
        }
        bh[kk] = v; bx[kk] = w;
    }

    float bias_[4];
#pragma unroll
    for (int r = 0; r < 4; r++) bias_[r] = bih[r * 512 + j_own] + bhh[r * 512 + j_own];

    // ---- one-time grid start barrier: all prefills visible before any write --
    {
        asm volatile("s_waitcnt vmcnt(0)" ::: "memory");
        __syncthreads();
        if (tid == 0) {
            __hip_atomic_fetch_add(bar + 1023, 1u, __ATOMIC_RELAXED,
                                   __HIP_MEMORY_SCOPE_AGENT);
            for (;;) {
                unsigned v = load_flag(bar + 1023);
                if (v >= 256u) break;
                __builtin_amdgcn_s_sleep(8);
            }
        }
        __syncthreads();
    }

    float c_state = 0.f;
    const unsigned short* xteam = xfrag + (size_t)q * T_ * TILE_;

    for (int s = 0; s < T_; s++) {
        const int t = dir ? (T_ - 1 - s) : s;
        const int tprev = dir ? (t + 1) : (t - 1);
        f32x4 ac0 = {0.f,0.f,0.f,0.f}, ac1 = {0.f,0.f,0.f,0.f};
        f32x4 ac2 = {0.f,0.f,0.f,0.f}, ac3 = {0.f,0.f,0.f,0.f};

        // ---- x phase: cached fragment loads + 4-chain MFMAs ----
        {
            const unsigned short* xp = xteam + (size_t)t * TILE_ + lane * 8;
            s8v xa[16];
#pragma unroll
            for (int kk = 0; kk < 16; kk++) xa[kk] = *(const s8v*)(xp + kk * 512);
#pragma unroll
            for (int m = 0; m < 4; m++) {
                mfma_bf16(ac0, xa[4 * m],     bx[4 * m]);
                mfma_bf16(ac1, xa[4 * m + 1], bx[4 * m + 1]);
                mfma_bf16(ac2, xa[4 * m + 2], bx[4 * m + 2]);
                mfma_bf16(ac3, xa[4 * m + 3], bx[4 * m + 3]);
            }
        }

        if (s > 0) {
            // ---- h tile, first attempt = PLAIN CACHED (L2-shared across the
            //      team's XCD). Fence pins issue after the x phase (R13 lesson:
            //      earlier issue -> always sentinel -> retry storm). ----
            asm volatile("" ::: "memory");
            s8v hv4[4];
#pragma unroll
            for (int u = 0; u < 4; u++) {
                int ch = tid + u * 256;
                int r = ch >> 6, c = ch & 63;
                hv4[u] = *(const s8v*)(h_hist +
                        (((size_t)dir * T_ + tprev) * B_ + (b0 + r)) * H_ + c * 8);
            }
            // ---- sentinel verify; dirty -> bypass retry (R10 shape) ----
            for (;;) {
                bool dirty = false;
#pragma unroll
                for (int u = 0; u < 4; u++) {
                    u4v w = *(u4v*)&hv4[u];
#pragma unroll
                    for (int e = 0; e < 4; e++) dirty |= (w[e] == SENT_);
                }
                if (__ballot(dirty) == 0ull) break;
                __builtin_amdgcn_s_sleep(1);
#pragma unroll
                for (int u = 0; u < 4; u++) {
                    int ch = tid + u * 256;
                    int r = ch >> 6, c = ch & 63;
                    asm volatile("global_load_dwordx4 %0, %1, off sc0 sc1"
                        : "=v"(hv4[u])
                        : "v"(h_hist +
                              (((size_t)dir * T_ + tprev) * B_ + (b0 + r)) * H_ + c * 8));
                }
                asm volatile("s_waitcnt vmcnt(0)" ::: "memory");
                __builtin_amdgcn_sched_barrier(0);
            }
            // ---- LDS stage + h-MFMAs (R10 verbatim) ----
            unsigned short* buf = Abuf[s & 1];
#pragma unroll
            for (int u = 0; u < 4; u++) {
                int ch = tid + u * 256;
                int r = ch >> 6, c = ch & 63;
                *(s8v*)(buf + r * 512 + ((c ^ (r & 7)) << 3)) = hv4[u];
            }
            __syncthreads();                       // barrier 1: stage-ready
#pragma unroll
            for (int kk = 0; kk < 16; kk++) {
                int slot = (kk * 4 + kgrp) ^ (arow & 7);
                s8v a = *(const s8v*)(buf + arow * 512 + slot * 8);
                if      ((kk & 3) == 0) mfma_bf16(ac0, a, bh[kk]);
                else if ((kk & 3) == 1) mfma_bf16(ac1, a, bh[kk]);
                else if ((kk & 3) == 2) mfma_bf16(ac2, a, bh[kk]);
                else                    mfma_bf16(ac3, a, bh[kk]);
            }
        }

        float acc[4];
#pragma unroll
        for (int r = 0; r < 4; r++) acc[r] = (ac0[r] + ac1[r]) + (ac2[r] + ac3[r]);

        // ---- Eklundh 4x4 transpose across g (lane masks 4, 8) ----
        float p0 = __shfl_xor(acc[0], 4, 64);
        float p1 = __shfl_xor(acc[1], 4, 64);
        float p2 = __shfl_xor(acc[2], 4, 64);
        float p3 = __shfl_xor(acc[3], 4, 64);
        const bool glo = (g_own & 1);
        float m1_0 = glo ? p1 : acc[0];
        float m1_1 = glo ? acc[1] : p0;
        float m1_2 = glo ? p3 : acc[2];
        float m1_3 = glo ? acc[3] : p2;
        float q0 = __shfl_xor(m1_0, 8, 64);
        float q1 = __shfl_xor(m1_1, 8, 64);
        float q2 = __shfl_xor(m1_2, 8, 64);
        float q3 = __shfl_xor(m1_3, 8, 64);
        const bool ghi = (g_own >> 1) & 1;
        float gi = (ghi ? q2   : m1_0) + bias_[0];
        float gf = (ghi ? q3   : m1_1) + bias_[1];
        float gg = (ghi ? m1_2 : q0)   + bias_[2];
        float go = (ghi ? m1_3 : q1)   + bias_[3];

        // ---- activations; thread owns (b0 + kgrp*4 + g_own, j_own) ----
        c_state = sigm(gf) * c_state + sigm(gi) * tanh_f(gg);
        float hv = sigm(go) * tanh_f(c_state);

        // ---- publish: 512B LDS repack -> wave0 coalesced 16B bursts ----
        h_tile[kgrp * 4 + g_own][wave * 4 + jloc] = f2bf(hv);
        __syncthreads();                           // barrier 2: h_tile-ready
        if (wave == 0 && lane < 32) {
            int row = lane >> 1, seg = lane & 1;
            s8v v = *(const s8v*)&h_tile[row][seg * 8];
            store_llc_b128(h_hist +
                (((size_t)dir * T_ + t) * B_ + (b0 + row)) * H_ + j0 + seg * 8, v);
        }
        // no ack, no flag: consumers sentinel-verify
    }
}

// ---------------------------------------------------------------------------
// Kernel 3: feats[b,t,k] = [h_f|h_b] . W_out[k] + b_out[k].
// ---------------------------------------------------------------------------
__global__ __launch_bounds__(256) void feats_kernel(
    const unsigned short* __restrict__ h_hist,
    const float* __restrict__ W_out, const float* __restrict__ b_out,
    float* __restrict__ feats)
{
    __shared__ float wlds[NTAGS * 1024];
    __shared__ float blds[NTAGS];
    for (int i = threadIdx.x; i < NTAGS * 1024; i += 256) wlds[i] = W_out[i];
    if (threadIdx.x < NTAGS) blds[threadIdx.x] = b_out[threadIdx.x];
    __syncthreads();

    int lane = threadIdx.x & 63;
    int row0 = blockIdx.x * 32 + (threadIdx.x >> 6) * 8;
    for (int rr = 0; rr < 8; rr++) {
        int wid = row0 + rr;                 // row = b*T + t
        int b = wid >> 9, t = wid & 511;
        s8v vf = *(const s8v*)(h_hist + (((size_t)0 * T_ + t) * B_ + b) * H_ + lane * 8);
        s8v vb = *(const s8v*)(h_hist + (((size_t)1 * T_ + t) * B_ + b) * H_ + lane * 8);
        float xf[8], xb[8];
#pragma unroll
        for (int j = 0; j < 8; j++) {
            xf[j] = bf2f((unsigned short)vf[j]);
            xb[j] = bf2f((unsigned short)vb[j]);
        }
#pragma unroll
        for (int k = 0; k < NTAGS; k++) {
            float acc = 0.f;
#pragma unroll
            for (int j = 0; j < 8; j++) acc += xf[j] * wlds[k * 1024 + lane * 8 + j];
#pragma unroll
            for (int j = 0; j < 8; j++) acc += xb[j] * wlds[k * 1024 + 512 + lane * 8 + j];
#pragma unroll
            for (int off = 32; off > 0; off >>= 1) acc += __shfl_xor(acc, off, 64);
            if (lane == 0) feats[(size_t)wid * NTAGS + k] = acc + blds[k];
        }
    }
}

// ---------------------------------------------------------------------------
// Kernel 4: Viterbi. One wave per batch item; lane j<12 owns tag j.
// ---------------------------------------------------------------------------
__global__ __launch_bounds__(64) void viterbi_kernel(
    const float* __restrict__ feats, const float* __restrict__ trans,
    float* __restrict__ out)
{
    const int b = blockIdx.x;
    const int j = threadIdx.x;
    const int jj = (j < NTAGS) ? j : 0;    // safe index for inactive lanes
    __shared__ unsigned char bp[T_][NTAGS];
    __shared__ float flds[T_ * NTAGS];     // 24KB

    {
        const float4* src = (const float4*)(feats + (size_t)b * T_ * NTAGS);
        float4* dst = (float4*)flds;
        for (int i = j; i < T_ * NTAGS / 4; i += 64) dst[i] = src[i];
    }
    __syncthreads();

    float trow[NTAGS];
#pragma unroll
    for (int p = 0; p < NTAGS; p++) trow[p] = trans[jj * NTAGS + p];
    float fv = (j == START_ID_) ? 0.f : -10000.f;

    for (int t = 0; t < T_; t++) {
        float feat = flds[t * NTAGS + jj];
        float best = -3.4e38f; int bestp = 0;
#pragma unroll
        for (int p = 0; p < NTAGS; p++) {
            float sp = __shfl(fv, p, 64) + trow[p];    // all lanes participate
            if (sp > best) { best = sp; bestp = p; }   // strict > == argmax-first
        }
        fv = best + feat;
        if (j < NTAGS) bp[t][j] = (unsigned char)bestp;
    }

    float term = (j < NTAGS) ? (fv + trans[STOP_ID_ * NTAGS + jj]) : -3.4e38f;
    float best = -3.4e38f; int bt = 0;
#pragma unroll
    for (int p = 0; p < NTAGS; p++) {
        float v = __shfl(term, p, 64);
        if (v > best) { best = v; bt = p; }
    }
    __syncthreads();
    if (j == 0) {
        out[b] = best;
        int tag = bt;
        for (int t = T_ - 1; t >= 0; t--) {
            out[B_ + (size_t)b * T_ + t] = (float)tag;
            tag = bp[t][tag];
        }
    }
}

// ---------------------------------------------------------------------------
extern "C" void kernel_launch(void* const* d_in, const int* in_sizes, int n_in,
                              void* d_out, int out_size, void* d_ws, size_t ws_size,
                              hipStream_t stream)
{
    (void)in_sizes; (void)n_in; (void)out_size; (void)ws_size;
    const int*   x     = (const int*)  d_in[0];
    const float* embed = (const float*)d_in[1];
    const float* Wih_f = (const float*)d_in[2];
    const float* Whh_f = (const float*)d_in[3];
    const float* bih_f = (const float*)d_in[4];
    const float* bhh_f = (const float*)d_in[5];
    const float* Wih_b = (const float*)d_in[6];
    const float* Whh_b = (const float*)d_in[7];
    const float* bih_b = (const float*)d_in[8];
    const float* bhh_b = (const float*)d_in[9];
    const float* W_out = (const float*)d_in[10];
    const float* b_out = (const float*)d_in[11];
    const float* trans = (const float*)d_in[12];

    char* ws = (char*)d_ws;
    const size_t XF_BYTES   = (size_t)4 * T_ * TILE_ * 2;     // 32 MB
    const size_t HIST_BYTES = (size_t)2 * T_ * B_ * H_ * 2;   // 64 MB
    const size_t FEAT_BYTES = (size_t)B_ * T_ * NTAGS * 4;    // 1.5 MB
    unsigned short* xfrag  = (unsigned short*)(ws);
    unsigned short* h_hist = (unsigned short*)(ws + XF_BYTES);
    float*          feats  = (float*)(ws + XF_BYTES + HIST_BYTES);
    unsigned*       bar    = (unsigned*)(ws + XF_BYTES + HIST_BYTES + FEAT_BYTES);

    hipMemsetAsync(bar, 0, 4096, stream);
    embed_gather<<<dim3(2048), dim3(256), 0, stream>>>(x, embed, xfrag);
    lstm_persistent<<<dim3(256), dim3(256), 0, stream>>>(xfrag,
        Wih_f, Whh_f, bih_f, bhh_f, Wih_b, Whh_b, bih_b, bhh_b, h_hist, bar);
    feats_kernel<<<dim3(1024), dim3(256), 0, stream>>>(h_hist, W_out, b_out, feats);
    viterbi_kernel<<<dim3(B_), dim3(64), 0, stream>>>(feats, trans, (float*)d_out);
}

// Round 24
// 1400.287 us; speedup vs baseline: 1.2125x; 1.0010x over previous
//
#include <hip/hip_runtime.h>

// ---------------------------------------------------------------------------
// NER CRF LSTM on MI355X. Round 23: restore R14 (empirical best: 1178us lstm,
// 1403us total). Nine variants around this structure all regressed or failed:
//  - earlier/any speculation of h (R13/R15): sentinel storm or spill bug
//  - x warming (R16/R21): foregrounds traffic at vm-drains / breaks write-
//    combining (WRITE_SIZE +66MB in R21)
//  - lgkm-only barriers (R21): publish stream loses coalescing
//  - no-LDS fragment h (R18): 4x redundant LLC pulls
//  - 16-member teams (R20): pricier 8-wave barriers, less issue concurrency
// R14 = R10 structure + cached-first-attempt h read (L2 skew compression),
// sentinel data-as-flag protocol, zero flags/acks. This is the converged
// design: per-step cost ~= 2 LLC RTTs + ~2000cy serial compute (latency-
// bound; MfmaUtil/HBM% are not the binding constraints).
// ws layout: xfrag 32MB | h_hist 64MB | feats 1.5MB | bar 4KB (start ctr).
// ---------------------------------------------------------------------------

#define B_ 64
#define T_ 512
#define E_ 512
#define H_ 512
#define NTAGS 12
#define START_ID_ 10
#define STOP_ID_ 11
#define TILE_ 8192            // xfrag tile elems: 64 chunks * 16 rows * 8
#define SENT_ 0x7FC17FC1u     // dword of two bf16 NaNs: never real h data

typedef __attribute__((ext_vector_type(8))) short s8v;     // 8 x bf16 bits
typedef __attribute__((ext_vector_type(4))) float f32x4;   // MFMA acc
typedef __attribute__((ext_vector_type(4))) unsigned u4v;  // dword view
typedef __attribute__((ext_vector_type(2))) unsigned u2v;  // 8B store payload

__device__ __forceinline__ unsigned short f2bf(float f) {
    unsigned u = __float_as_uint(f);
    u += 0x7fffu + ((u >> 16) & 1u);           // RNE
    return (unsigned short)(u >> 16);
}
__device__ __forceinline__ float bf2f(unsigned short h) {
    return __uint_as_float(((unsigned)h) << 16);
}
__device__ __forceinline__ float sigm(float x) { return 1.f / (1.f + __expf(-x)); }
__device__ __forceinline__ float tanh_f(float x) { return 1.f - 2.f / (__expf(2.f * x) + 1.f); }

__device__ __forceinline__ void mfma_bf16(f32x4& c, s8v a, s8v b) {
    asm("v_mfma_f32_16x16x32_bf16 %0, %1, %2, %0" : "+v"(c) : "v"(a), "v"(b));
}

// Device-coherent (bypass L1/L2, LLC) ops.
__device__ __forceinline__ unsigned load_flag(const unsigned* p) {
    unsigned r;
    asm volatile("global_load_dword %0, %1, off sc0 sc1\n\ts_waitcnt vmcnt(0)"
                 : "=v"(r) : "v"(p) : "memory");
    return r;
}
__device__ __forceinline__ void store_llc_b64(unsigned short* p, u2v v) {
    asm volatile("global_store_dwordx2 %0, %1, off sc0 sc1" :: "v"(p), "v"(v) : "memory");
}
__device__ __forceinline__ void store_llc_b128(unsigned short* p, s8v v) {
    asm volatile("global_store_dwordx4 %0, %1, off sc0 sc1" :: "v"(p), "v"(v) : "memory");
}

// ---------------------------------------------------------------------------
// Kernel 1: embedding gather + fp32->bf16 into fragment-linear tiles.
// ---------------------------------------------------------------------------
__global__ __launch_bounds__(256) void embed_gather(
    const int* __restrict__ x, const float* __restrict__ embed,
    unsigned short* __restrict__ xfrag)
{
    const int q = blockIdx.x >> 9;          // batch group 0..3
    const int t = blockIdx.x & 511;
    const int fr = threadIdx.x & 15;
    const int c  = threadIdx.x >> 4;        // 0..15, owns dims c*32..c*32+31
    const int tok = x[(size_t)(q * 16 + fr) * T_ + t];
    const float* src = embed + (size_t)tok * E_ + c * 32;
    unsigned short* dst = xfrag + (size_t)(q * T_ + t) * TILE_;
#pragma unroll
    for (int g = 0; g < 4; g++) {
        float4 a = *(const float4*)(src + g * 8);
        float4 b = *(const float4*)(src + g * 8 + 4);
        s8v o;
        o[0] = (short)f2bf(a.x); o[1] = (short)f2bf(a.y);
        o[2] = (short)f2bf(a.z); o[3] = (short)f2bf(a.w);
        o[4] = (short)f2bf(b.x); o[5] = (short)f2bf(b.y);
        o[6] = (short)f2bf(b.z); o[7] = (short)f2bf(b.w);
        *(s8v*)(dst + (c * 4 + g) * 128 + fr * 8) = o;
    }
}

// ---------------------------------------------------------------------------
// Kernel 2: persistent BiLSTM. 256 blocks x 256 threads, 1 block/CU.
// ---------------------------------------------------------------------------
__global__ __launch_bounds__(256, 1) void lstm_persistent(
    const unsigned short* __restrict__ xfrag,
    const float* __restrict__ Wih_f, const float* __restrict__ Whh_f,
    const float* __restrict__ bih_f, const float* __restrict__ bhh_f,
    const float* __restrict__ Wih_b, const float* __restrict__ Whh_b,
    const float* __restrict__ bih_b, const float* __restrict__ bhh_b,
    unsigned short* __restrict__ h_hist, unsigned* __restrict__ bar)
{
    const int team = blockIdx.x & 7;
    const int dir = team & 1;
    const int q   = team >> 1;               // batch quarter
    const int b0  = q * 16;
    const int j0  = (blockIdx.x >> 3) * 16;  // h-dim base
    const int tid  = threadIdx.x;
    const int wave = tid >> 6;
    const int lane = tid & 63;

    const int fr = lane & 15;
    const int fk = (lane >> 4) * 8;
    const int arow = lane & 15;
    const int kgrp = lane >> 4;
    const int g_own = (lane >> 2) & 3;
    const int jloc  = lane & 3;
    const int j_own = j0 + wave * 4 + jloc;

    const float* Wih = dir ? Wih_b : Wih_f;
    const float* Whh = dir ? Whh_b : Whh_f;
    const float* bih = dir ? bih_b : bih_f;
    const float* bhh = dir ? bhh_b : bhh_f;

    __shared__ __align__(16) unsigned short Abuf[2][16 * 512]; // h double-buffer, swizzled
    __shared__ __align__(16) unsigned short h_tile[16][16];    // 512B repack tile

    // ---- sentinel-prefill this block's OWN h slice (all t), write-through ----
    {
        const int row = lane >> 2;
        const int dwp = lane & 3;
        u2v sv; sv[0] = SENT_; sv[1] = SENT_;
        for (int tt = wave; tt < T_; tt += 4) {
            unsigned short* p = h_hist +
                (((size_t)dir * T_ + tt) * B_ + (b0 + row)) * H_ + j0 + dwp * 4;
            store_llc_b64(p, sv);
        }
    }

    // ---- weight B-fragments (wave-column layout). ----
    const int wrow = (fr >> 2) * 512 + j0 + wave * 4 + (fr & 3);
    const float* whr = Whh + (size_t)wrow * 512;
    const float* wxr = Wih + (size_t)wrow * 512;
    s8v bh[16], bx[16];
#pragma unroll
    for (int kk = 0; kk < 16; kk++) {
        s8v v, w;
#pragma unroll
        for (int j = 0; j < 8; j++) {
            v[j] = (short)f2bf(whr[kk * 32 + fk + j]);
            w[j] = (short)f2bf(wxr[kk * 32 + fk + j]);
        }
        bh[kk] = v; bx[kk] = w;
    }

    float bias_[4];
#pragma unroll
    for (int r = 0; r < 4; r++) bias_[r] = bih[r * 512 + j_own] + bhh[r * 512 + j_own];

    // ---- one-time grid start barrier: all prefills visible before any write --
    {
        asm volatile("s_waitcnt vmcnt(0)" ::: "memory");
        __syncthreads();
        if (tid == 0) {
            __hip_atomic_fetch_add(bar + 1023, 1u, __ATOMIC_RELAXED,
                                   __HIP_MEMORY_SCOPE_AGENT);
            for (;;) {
                unsigned v = load_flag(bar + 1023);
                if (v >= 256u) break;
                __builtin_amdgcn_s_sleep(8);
            }
        }
        __syncthreads();
    }

    float c_state = 0.f;
    const unsigned short* xteam = xfrag + (size_t)q * T_ * TILE_;

    for (int s = 0; s < T_; s++) {
        const int t = dir ? (T_ - 1 - s) : s;
        const int tprev = dir ? (t + 1) : (t - 1);
        f32x4 ac0 = {0.f,0.f,0.f,0.f}, ac1 = {0.f,0.f,0.f,0.f};
        f32x4 ac2 = {0.f,0.f,0.f,0.f}, ac3 = {0.f,0.f,0.f,0.f};

        // ---- x phase: cached fragment loads + 4-chain MFMAs ----
        {
            const unsigned short* xp = xteam + (size_t)t * TILE_ + lane * 8;
            s8v xa[16];
#pragma unroll
            for (int kk = 0; kk < 16; kk++) xa[kk] = *(const s8v*)(xp + kk * 512);
#pragma unroll
            for (int m = 0; m < 4; m++) {
                mfma_bf16(ac0, xa[4 * m],     bx[4 * m]);
                mfma_bf16(ac1, xa[4 * m + 1], bx[4 * m + 1]);
                mfma_bf16(ac2, xa[4 * m + 2], bx[4 * m + 2]);
                mfma_bf16(ac3, xa[4 * m + 3], bx[4 * m + 3]);
            }
        }

        if (s > 0) {
            // ---- h tile, first attempt = PLAIN CACHED (L2-shared across the
            //      team's XCD). Fence pins issue after the x phase (R13 lesson:
            //      earlier issue -> always sentinel -> retry storm). ----
            asm volatile("" ::: "memory");
            s8v hv4[4];
#pragma unroll
            for (int u = 0; u < 4; u++) {
                int ch = tid + u * 256;
                int r = ch >> 6, c = ch & 63;
                hv4[u] = *(const s8v*)(h_hist +
                        (((size_t)dir * T_ + tprev) * B_ + (b0 + r)) * H_ + c * 8);
            }
            // ---- sentinel verify; dirty -> bypass retry (R10 shape) ----
            for (;;) {
                bool dirty = false;
#pragma unroll
                for (int u = 0; u < 4; u++) {
                    u4v w = *(u4v*)&hv4[u];
#pragma unroll
                    for (int e = 0; e < 4; e++) dirty |= (w[e] == SENT_);
                }
                if (__ballot(dirty) == 0ull) break;
                __builtin_amdgcn_s_sleep(1);
#pragma unroll
                for (int u = 0; u < 4; u++) {
                    int ch = tid + u * 256;
                    int r = ch >> 6, c = ch & 63;
                    asm volatile("global_load_dwordx4 %0, %1, off sc0 sc1"
                        : "=v"(hv4[u])
                        : "v"(h_hist +
                              (((size_t)dir * T_ + tprev) * B_ + (b0 + r)) * H_ + c * 8));
                }
                asm volatile("s_waitcnt vmcnt(0)" ::: "memory");
                __builtin_amdgcn_sched_barrier(0);
            }
            // ---- LDS stage + h-MFMAs (R10 verbatim) ----
            unsigned short* buf = Abuf[s & 1];
#pragma unroll
            for (int u = 0; u < 4; u++) {
                int ch = tid + u * 256;
                int r = ch >> 6, c = ch & 63;
                *(s8v*)(buf + r * 512 + ((c ^ (r & 7)) << 3)) = hv4[u];
            }
            __syncthreads();                       // barrier 1: stage-ready
#pragma unroll
            for (int kk = 0; kk < 16; kk++) {
                int slot = (kk * 4 + kgrp) ^ (arow & 7);
                s8v a = *(const s8v*)(buf + arow * 512 + slot * 8);
                if      ((kk & 3) == 0) mfma_bf16(ac0, a, bh[kk]);
                else if ((kk & 3) == 1) mfma_bf16(ac1, a, bh[kk]);
                else if ((kk & 3) == 2) mfma_bf16(ac2, a, bh[kk]);
                else                    mfma_bf16(ac3, a, bh[kk]);
            }
        }

        float acc[4];
#pragma unroll
        for (int r = 0; r < 4; r++) acc[r] = (ac0[r] + ac1[r]) + (ac2[r] + ac3[r]);

        // ---- Eklundh 4x4 transpose across g (lane masks 4, 8) ----
        float p0 = __shfl_xor(acc[0], 4, 64);
        float p1 = __shfl_xor(acc[1], 4, 64);
        float p2 = __shfl_xor(acc[2], 4, 64);
        float p3 = __shfl_xor(acc[3], 4, 64);
        const bool glo = (g_own & 1);
        float m1_0 = glo ? p1 : acc[0];
        float m1_1 = glo ? acc[1] : p0;
        float m1_2 = glo ? p3 : acc[2];
        float m1_3 = glo ? acc[3] : p2;
        float q0 = __shfl_xor(m1_0, 8, 64);
        float q1 = __shfl_xor(m1_1, 8, 64);
        float q2 = __shfl_xor(m1_2, 8, 64);
        float q3 = __shfl_xor(m1_3, 8, 64);
        const bool ghi = (g_own >> 1) & 1;
        float gi = (ghi ? q2   : m1_0) + bias_[0];
        float gf = (ghi ? q3   : m1_1) + bias_[1];
        float gg = (ghi ? m1_2 : q0)   + bias_[2];
        float go = (ghi ? m1_3 : q1)   + bias_[3];

        // ---- activations; thread owns (b0 + kgrp*4 + g_own, j_own) ----
        c_state = sigm(gf) * c_state + sigm(gi) * tanh_f(gg);
        float hv = sigm(go) * tanh_f(c_state);

        // ---- publish: 512B LDS repack -> wave0 coalesced 16B bursts ----
        h_tile[kgrp * 4 + g_own][wave * 4 + jloc] = f2bf(hv);
        __syncthreads();                           // barrier 2: h_tile-ready
        if (wave == 0 && lane < 32) {
            int row = lane >> 1, seg = lane & 1;
            s8v v = *(const s8v*)&h_tile[row][seg * 8];
            store_llc_b128(h_hist +
                (((size_t)dir * T_ + t) * B_ + (b0 + row)) * H_ + j0 + seg * 8, v);
        }
        // no ack, no flag: consumers sentinel-verify
    }
}

// ---------------------------------------------------------------------------
// Kernel 3: feats[b,t,k] = [h_f|h_b] . W_out[k] + b_out[k].
// ---------------------------------------------------------------------------
__global__ __launch_bounds__(256) void feats_kernel(
    const unsigned short* __restrict__ h_hist,
    const float* __restrict__ W_out, const float* __restrict__ b_out,
    float* __restrict__ feats)
{
    __shared__ float wlds[NTAGS * 1024];
    __shared__ float blds[NTAGS];
    for (int i = threadIdx.x; i < NTAGS * 1024; i += 256) wlds[i] = W_out[i];
    if (threadIdx.x < NTAGS) blds[threadIdx.x] = b_out[threadIdx.x];
    __syncthreads();

    int lane = threadIdx.x & 63;
    int row0 = blockIdx.x * 32 + (threadIdx.x >> 6) * 8;
    for (int rr = 0; rr < 8; rr++) {
        int wid = row0 + rr;                 // row = b*T + t
        int b = wid >> 9, t = wid & 511;
        s8v vf = *(const s8v*)(h_hist + (((size_t)0 * T_ + t) * B_ + b) * H_ + lane * 8);
        s8v vb = *(const s8v*)(h_hist + (((size_t)1 * T_ + t) * B_ + b) * H_ + lane * 8);
        float xf[8], xb[8];
#pragma unroll
        for (int j = 0; j < 8; j++) {
            xf[j] = bf2f((unsigned short)vf[j]);
            xb[j] = bf2f((unsigned short)vb[j]);
        }
#pragma unroll
        for (int k = 0; k < NTAGS; k++) {
            float acc = 0.f;
#pragma unroll
            for (int j = 0; j < 8; j++) acc += xf[j] * wlds[k * 1024 + lane * 8 + j];
#pragma unroll
            for (int j = 0; j < 8; j++) acc += xb[j] * wlds[k * 1024 + 512 + lane * 8 + j];
#pragma unroll
            for (int off = 32; off > 0; off >>= 1) acc += __shfl_xor(acc, off, 64);
            if (lane == 0) feats[(size_t)wid * NTAGS + k] = acc + blds[k];
        }
    }
}

// ---------------------------------------------------------------------------
// Kernel 4: Viterbi. One wave per batch item; lane j<12 owns tag j.
// ---------------------------------------------------------------------------
__global__ __launch_bounds__(64) void viterbi_kernel(
    const float* __restrict__ feats, const float* __restrict__ trans,
    float* __restrict__ out)
{
    const int b = blockIdx.x;
    const int j = threadIdx.x;
    const int jj = (j < NTAGS) ? j : 0;    // safe index for inactive lanes
    __shared__ unsigned char bp[T_][NTAGS];
    __shared__ float flds[T_ * NTAGS];     // 24KB

    {
        const float4* src = (const float4*)(feats + (size_t)b * T_ * NTAGS);
        float4* dst = (float4*)flds;
        for (int i = j; i < T_ * NTAGS / 4; i += 64) dst[i] = src[i];
    }
    __syncthreads();

    float trow[NTAGS];
#pragma unroll
    for (int p = 0; p < NTAGS; p++) trow[p] = trans[jj * NTAGS + p];
    float fv = (j == START_ID_) ? 0.f : -10000.f;

    for (int t = 0; t < T_; t++) {
        float feat = flds[t * NTAGS + jj];
        float best = -3.4e38f; int bestp = 0;
#pragma unroll
        for (int p = 0; p < NTAGS; p++) {
            float sp = __shfl(fv, p, 64) + trow[p];    // all lanes participate
            if (sp > best) { best = sp; bestp = p; }   // strict > == argmax-first
        }
        fv = best + feat;
        if (j < NTAGS) bp[t][j] = (unsigned char)bestp;
    }

    float term = (j < NTAGS) ? (fv + trans[STOP_ID_ * NTAGS + jj]) : -3.4e38f;
    float best = -3.4e38f; int bt = 0;
#pragma unroll
    for (int p = 0; p < NTAGS; p++) {
        float v = __shfl(term, p, 64);
        if (v > best) { best = v; bt = p; }
    }
    __syncthreads();
    if (j == 0) {
        out[b] = best;
        int tag = bt;
        for (int t = T_ - 1; t >= 0; t--) {
            out[B_ + (size_t)b * T_ + t] = (float)tag;
            tag = bp[t][tag];
        }
    }
}

// ---------------------------------------------------------------------------
extern "C" void kernel_launch(void* const* d_in, const int* in_sizes, int n_in,
                              void* d_out, int out_size, void* d_ws, size_t ws_size,
                              hipStream_t stream)
{
    (void)in_sizes; (void)n_in; (void)out_size; (void)ws_size;
    const int*   x     = (const int*)  d_in[0];
    const float* embed = (const float*)d_in[1];
    const float* Wih_f = (const float*)d_in[2];
    const float* Whh_f = (const float*)d_in[3];
    const float* bih_f = (const float*)d_in[4];
    const float* bhh_f = (const float*)d_in[5];
    const float* Wih_b = (const float*)d_in[6];
    const float* Whh_b = (const float*)d_in[7];
    const float* bih_b = (const float*)d_in[8];
    const float* bhh_b = (const float*)d_in[9];
    const float* W_out = (const float*)d_in[10];
    const float* b_out = (const float*)d_in[11];
    const float* trans = (const float*)d_in[12];

    char* ws = (char*)d_ws;
    const size_t XF_BYTES   = (size_t)4 * T_ * TILE_ * 2;     // 32 MB
    const size_t HIST_BYTES = (size_t)2 * T_ * B_ * H_ * 2;   // 64 MB
    const size_t FEAT_BYTES = (size_t)B_ * T_ * NTAGS * 4;    // 1.5 MB
    unsigned short* xfrag  = (unsigned short*)(ws);
    unsigned short* h_hist = (unsigned short*)(ws + XF_BYTES);
    float*          feats  = (float*)(ws + XF_BYTES + HIST_BYTES);
    unsigned*       bar    = (unsigned*)(ws + XF_BYTES + HIST_BYTES + FEAT_BYTES);

    hipMemsetAsync(bar, 0, 4096, stream);
    embed_gather<<<dim3(2048), dim3(256), 0, stream>>>(x, embed, xfrag);
    lstm_persistent<<<dim3(256), dim3(256), 0, stream>>>(xfrag,
        Wih_f, Whh_f, bih_f, bhh_f, Wih_b, Whh_b, bih_b, bhh_b, h_hist, bar);
    feats_kernel<<<dim3(1024), dim3(256), 0, stream>>>(h_hist, W_out, b_out, feats);
    viterbi_kernel<<<dim3(B_), dim3(64), 0, stream>>>(feats, trans, (float*)d_out);
}